// Round 5
// baseline (1917.224 us; speedup 1.0000x reference)
//
#include <hip/hip_runtime.h>
#include <math.h>

// ULOSD keypoint autoencoder, fp32 direct convolutions.
// Round 8: wave-supply retune. Round-7 counters: flagship occupancy 35% --
// grid of 1024 blocks caps at 16 waves/CU (50%), and the unroll-1 ci loop
// exposes one VMEM+SMEM latency per iteration that 2.8 waves/SIMD can't hide
// (VALUBusy 57%). r2 tiles are cheap (acc<=32, 6 live loads), so halve NC and
// double the grid: 2048 blocks = 8 blocks/CU = 32 waves/CU = 100% cap.
// Cost: cross-cog input re-reads double (FETCH ~+50%) -- irrelevant at 5% HBM.
// enc6/tconvs excluded (FMA:VMEM ratio already thin at their sizes).

enum { ACT_ID = 0, ACT_LRELU = 1, ACT_SOFTPLUS = 2, ACT_RELU = 3 };

template<int ACT>
__device__ __forceinline__ float act_fn(float x) {
  if (ACT == ACT_LRELU)    return x >= 0.f ? x : 0.2f * x;
  if (ACT == ACT_SOFTPLUS) return fmaxf(x, 0.f) + log1pf(expf(-fabsf(x)));
  if (ACT == ACT_RELU)     return fmaxf(x, 0.f);
  return x;
}

// ---------------- stride-1 3x3 SAME conv, 2 output rows x CPT cols, NC couts ---
template<int ACT, int NC, int CPT, int CIN>
__global__ __launch_bounds__(256)
void conv_s1r2(const float* __restrict__ in, const float* __restrict__ w,
               const float* __restrict__ bias, float* __restrict__ out,
               int Cout, int H, int W) {
  const int cogs = Cout / NC;
  const int gx  = blockIdx.x;           // b*cogs + cog
  const int cog = gx % cogs;
  const int b   = gx / cogs;
  const int co0 = cog * NC;
  const int Wq  = W / CPT;
  const int Hp  = H >> 1;               // row pairs
  const int items = Hp * Wq;
  const int item  = blockIdx.y * 256 + threadIdx.x;
  if (item >= items) return;
  const int yp = item / Wq;
  const int x0 = (item - yp * Wq) * CPT;
  const int y0 = 2 * yp;                // output rows y0, y0+1; input y0-1..y0+2

  const int HW = H * W;
  const float* ib = in + (size_t)b * CIN * HW;

  const bool okT = (y0 > 0), okB = (y0 + 2 < H);
  const bool okL = (x0 > 0), okR = (x0 + CPT < W);
  const int xl = okL ? (x0 - 1) : 0;
  const int xr = okR ? (x0 + CPT) : 0;

  float acc[NC][2][CPT];
  #pragma unroll
  for (int u = 0; u < NC; ++u)
    #pragma unroll
    for (int o = 0; o < 2; ++o)
      #pragma unroll
      for (int q = 0; q < CPT; ++q) acc[u][o][q] = 0.f;

  #pragma unroll 1
  for (int ci = 0; ci < CIN; ++ci) {
    const float* p = ib + ci * HW;
    const float* wci = w + ((size_t)co0 * CIN + ci) * 9;
    #pragma unroll
    for (int r = 0; r < 4; ++r) {            // input rows y0-1+r
      const bool ok = (r == 0) ? okT : ((r == 3) ? okB : true);
      const int iy = ok ? (y0 - 1 + r) : 0;
      const float* row = p + iy * W;
      float v[CPT + 2];
      if (CPT == 4) {
        float  lf = row[xl];
        float4 m  = *(const float4*)(row + x0);
        float  rf = row[xr];
        v[0] = (ok && okL) ? lf : 0.f;
        v[1] = ok ? m.x : 0.f;
        v[2] = ok ? m.y : 0.f;
        v[3] = ok ? m.z : 0.f;
        v[4] = ok ? m.w : 0.f;
        v[5] = (ok && okR) ? rf : 0.f;
      } else if (CPT == 2) {
        float  lf = row[xl];
        float2 m  = *(const float2*)(row + x0);   // x0 even -> aligned
        float  rf = row[xr];
        v[0] = (ok && okL) ? lf : 0.f;
        v[1] = ok ? m.x : 0.f;
        v[2] = ok ? m.y : 0.f;
        v[3] = (ok && okR) ? rf : 0.f;
      } else {
        v[0] = (ok && okL) ? row[xl] : 0.f;
        #pragma unroll
        for (int q = 0; q < CPT; ++q) v[1 + q] = ok ? row[x0 + q] : 0.f;
        v[CPT + 1] = (ok && okR) ? row[xr] : 0.f;
      }
      // input row r -> out-row0 with wrow r (r<=2), out-row1 with wrow r-1 (r>=1)
      #pragma unroll
      for (int u = 0; u < NC; ++u) {
        const float* wp = wci + (size_t)u * CIN * 9;   // wave-uniform s_loads
        if (r <= 2) {
          const float w0 = wp[r * 3], w1 = wp[r * 3 + 1], w2 = wp[r * 3 + 2];
          #pragma unroll
          for (int q = 0; q < CPT; ++q)
            acc[u][0][q] += v[q] * w0 + v[q + 1] * w1 + v[q + 2] * w2;
        }
        if (r >= 1) {
          const float w0 = wp[(r-1) * 3], w1 = wp[(r-1) * 3 + 1], w2 = wp[(r-1) * 3 + 2];
          #pragma unroll
          for (int q = 0; q < CPT; ++q)
            acc[u][1][q] += v[q] * w0 + v[q + 1] * w1 + v[q + 2] * w2;
        }
      }
    }
  }

  #pragma unroll
  for (int u = 0; u < NC; ++u) {
    const float bv = bias[co0 + u];
    float* op = out + ((size_t)(b * Cout + co0 + u) * H + y0) * W + x0;
    #pragma unroll
    for (int o = 0; o < 2; ++o) {
      float* opo = op + o * W;
      if (CPT == 4) {
        float4 r4;
        r4.x = act_fn<ACT>(acc[u][o][0] + bv);
        r4.y = act_fn<ACT>(acc[u][o][1] + bv);
        r4.z = act_fn<ACT>(acc[u][o][2] + bv);
        r4.w = act_fn<ACT>(acc[u][o][3] + bv);
        *(float4*)opo = r4;
      } else if (CPT == 2) {
        float2 r2;
        r2.x = act_fn<ACT>(acc[u][o][0] + bv);
        r2.y = act_fn<ACT>(acc[u][o][1] + bv);
        *(float2*)opo = r2;
      } else {
        #pragma unroll
        for (int q = 0; q < CPT; ++q) opo[q] = act_fn<ACT>(acc[u][o][q] + bv);
      }
    }
  }
}

// ---------------- stride-2 3x3 SAME conv (pad_before=0, pad_after=1) -----------
template<int ACT, int NC, int CPT, int CIN>
__global__ __launch_bounds__(256)
void conv_s2(const float* __restrict__ in, const float* __restrict__ w,
             const float* __restrict__ bias, float* __restrict__ out,
             int Cout, int H, int W) {
  const int Ho = H >> 1, Wo = W >> 1;
  const int cogs = Cout / NC;
  const int gx  = blockIdx.x;
  const int cog = gx % cogs;
  const int b   = gx / cogs;
  const int co0 = cog * NC;
  const int Wq  = Wo / CPT;
  const int items = Ho * Wq;
  const int item  = blockIdx.y * 256 + threadIdx.x;
  if (item >= items) return;
  const int y  = item / Wq;
  const int x0 = (item - y * Wq) * CPT;
  const int ix = 2 * x0;

  const int HW = H * W;
  const float* ib = in + (size_t)b * CIN * HW;

  const int iy0 = 2 * y, iy1 = 2 * y + 1, iy2 = 2 * y + 2;
  const bool okB = (iy2 < H);
  const int iy2c = okB ? iy2 : 0;
  const bool okR = (ix + 2 * CPT < W);
  const int ixr  = okR ? (ix + 2 * CPT) : 0;

  float acc[NC][CPT];
  #pragma unroll
  for (int u = 0; u < NC; ++u)
    #pragma unroll
    for (int q = 0; q < CPT; ++q) acc[u][q] = 0.f;

  #pragma unroll 2
  for (int ci = 0; ci < CIN; ++ci) {
    const float* p = ib + ci * HW;
    const float* wci = w + ((size_t)co0 * CIN + ci) * 9;
    #pragma unroll
    for (int dy = 0; dy < 3; ++dy) {
      const int  ry    = (dy == 0) ? iy0 : ((dy == 1) ? iy1 : iy2c);
      const bool okRow = (dy < 2) || okB;
      const float* r = p + ry * W;
      float v[2 * CPT + 1];
      if (CPT == 4) {
        float4 m0 = *(const float4*)(r + ix);
        float4 m1 = *(const float4*)(r + ix + 4);
        float  rf = r[ixr];
        v[0] = okRow ? m0.x : 0.f; v[1] = okRow ? m0.y : 0.f;
        v[2] = okRow ? m0.z : 0.f; v[3] = okRow ? m0.w : 0.f;
        v[4] = okRow ? m1.x : 0.f; v[5] = okRow ? m1.y : 0.f;
        v[6] = okRow ? m1.z : 0.f; v[7] = okRow ? m1.w : 0.f;
        v[8] = (okRow && okR) ? rf : 0.f;
      } else if (CPT == 2) {
        float4 m0 = *(const float4*)(r + ix);
        float  rf = r[ixr];
        v[0] = okRow ? m0.x : 0.f; v[1] = okRow ? m0.y : 0.f;
        v[2] = okRow ? m0.z : 0.f; v[3] = okRow ? m0.w : 0.f;
        v[4] = (okRow && okR) ? rf : 0.f;
      } else {
        float2 m0 = *(const float2*)(r + ix);
        float  rf = r[ixr];
        v[0] = okRow ? m0.x : 0.f; v[1] = okRow ? m0.y : 0.f;
        v[2] = (okRow && okR) ? rf : 0.f;
      }
      #pragma unroll
      for (int u = 0; u < NC; ++u) {
        const float* wp = wci + u * CIN * 9 + dy * 3;
        const float w0 = wp[0], w1 = wp[1], w2 = wp[2];
        #pragma unroll
        for (int q = 0; q < CPT; ++q)
          acc[u][q] += v[2*q] * w0 + v[2*q + 1] * w1 + v[2*q + 2] * w2;
      }
    }
  }

  #pragma unroll
  for (int u = 0; u < NC; ++u) {
    const float bv = bias[co0 + u];
    float* op = out + ((size_t)(b * Cout + co0 + u) * Ho + y) * Wo + x0;
    if (CPT == 4) {
      float4 r4;
      r4.x = act_fn<ACT>(acc[u][0] + bv);
      r4.y = act_fn<ACT>(acc[u][1] + bv);
      r4.z = act_fn<ACT>(acc[u][2] + bv);
      r4.w = act_fn<ACT>(acc[u][3] + bv);
      *(float4*)op = r4;
    } else if (CPT == 2) {
      float2 r2;
      r2.x = act_fn<ACT>(acc[u][0] + bv);
      r2.y = act_fn<ACT>(acc[u][1] + bv);
      *(float2*)op = r2;
    } else {
      #pragma unroll
      for (int q = 0; q < CPT; ++q) op[q] = act_fn<ACT>(acc[u][q] + bv);
    }
  }
}

// ---------------- stride-2 3x3 SAME transposed conv ----------------------------
// out[2i,2j]=xtl*w00+xtr*w02+xbl*w20+xbr*w22; out[2i,2j+1]=xtr*w01+xbr*w21
// out[2i+1,2j]=xbl*w10+xbr*w12;               out[2i+1,2j+1]=xbr*w11
template<int ACT, int NC, int CIN>
__global__ __launch_bounds__(256)
void tconv(const float* __restrict__ in, const float* __restrict__ w,
           const float* __restrict__ bias, float* __restrict__ out,
           int Cout, int Hin) {
  const int cogs = Cout / NC;
  const int gx  = blockIdx.x;
  const int cog = gx % cogs;
  const int b   = gx / cogs;
  const int co0 = cog * NC;
  const int items = Hin * Hin;
  const int item  = blockIdx.y * 256 + threadIdx.x;
  if (item >= items) return;
  const int i = item / Hin;
  const int j = item - i * Hin;

  const float* ib = in + (size_t)b * CIN * items;
  const bool okT = (i > 0), okL = (j > 0);
  const int im = okT ? i - 1 : 0;
  const int jm = okL ? j - 1 : 0;

  float a00[NC], a01[NC], a10[NC], a11[NC];
  #pragma unroll
  for (int u = 0; u < NC; ++u) { a00[u]=0.f; a01[u]=0.f; a10[u]=0.f; a11[u]=0.f; }

  #pragma unroll 2
  for (int ci = 0; ci < CIN; ++ci) {
    const float* p = ib + ci * items;
    float xtl = p[im*Hin + jm]; xtl = (okT && okL) ? xtl : 0.f;
    float xtr = p[im*Hin + j];  xtr = okT ? xtr : 0.f;
    float xbl = p[i*Hin + jm];  xbl = okL ? xbl : 0.f;
    float xbr = p[i*Hin + j];
    const float* wci = w + ((size_t)co0 * CIN + ci) * 9;
    #pragma unroll
    for (int u = 0; u < NC; ++u) {
      const float* wp = wci + u * CIN * 9;
      const float w00 = wp[0], w01 = wp[1], w02 = wp[2];
      const float w10 = wp[3], w11 = wp[4], w12 = wp[5];
      const float w20 = wp[6], w21 = wp[7], w22 = wp[8];
      a00[u] += xtl*w00 + xtr*w02 + xbl*w20 + xbr*w22;
      a01[u] += xtr*w01 + xbr*w21;
      a10[u] += xbl*w10 + xbr*w12;
      a11[u] += xbr*w11;
    }
  }

  const int Ho = Hin * 2;
  #pragma unroll
  for (int u = 0; u < NC; ++u) {
    const float bv = bias[co0 + u];
    float* op = out + (size_t)(b * Cout + co0 + u) * Ho * Ho + (2*i) * Ho + 2*j;
    float2 t0, t1;
    t0.x = act_fn<ACT>(a00[u] + bv); t0.y = act_fn<ACT>(a01[u] + bv);
    t1.x = act_fn<ACT>(a10[u] + bv); t1.y = act_fn<ACT>(a11[u] + bv);
    *(float2*)op = t0;
    *(float2*)(op + Ho) = t1;
  }
}

// ---------------- keypoint reductions: S = sum R, Sh = sum R*h, Sw = sum R*w ----
__global__ __launch_bounds__(64)
void kp_reduce(const float* __restrict__ R, float* __restrict__ S,
               float* __restrict__ Sh, float* __restrict__ Sw) {
  const int bk = blockIdx.x;       // b*K + k, 16x16 maps
  const int t = threadIdx.x;       // 64
  const float* p = R + (size_t)bk * 256;
  float s = 0.f, sh = 0.f, sw = 0.f;
  #pragma unroll
  for (int q = 0; q < 4; ++q) {
    int idx = t + q * 64;
    float v = p[idx];
    s  += v;
    sh += v * (float)(idx >> 4);
    sw += v * (float)(idx & 15);
  }
  #pragma unroll
  for (int off = 32; off > 0; off >>= 1) {
    s  += __shfl_down(s, off);
    sh += __shfl_down(sh, off);
    sw += __shfl_down(sw, off);
  }
  if (t == 0) { S[bk] = s; Sh[bk] = sh; Sw[bk] = sw; }
}

// ---------------- gaussian blob maps -------------------------------------------
__global__ __launch_bounds__(256)
void kp_maps(const float* __restrict__ S, const float* __restrict__ Sh,
             const float* __restrict__ Sw, float* __restrict__ maps, int K) {
  const int bk = blockIdx.x;
  const int b = bk / K;
  const int t = threadIdx.x;       // 256 = 16x16
  const float s   = S[bk];
  const float den = S[b * K + (K - 1)];
  const float mu  = s * (1.0f / 256.0f);
  const float c0  = Sh[bk] / den;
  const float c1  = Sw[bk] / den;
  const float u = (float)(t >> 4);
  const float v = (float)(t & 15);
  const float d2 = (u - c0) * (u - c0) + (v - c1) * (v - c1);
  maps[(size_t)bk * 256 + t] = mu * expf(-0.5f * d2);
}

extern "C" void kernel_launch(void* const* d_in, const int* in_sizes, int n_in,
                              void* d_out, int out_size, void* d_ws, size_t ws_size,
                              hipStream_t stream) {
  const int B = 32;  // 4 * 8
  const float* x = (const float*)d_in[0];
  const float* ew[7]; const float* eb[7];
  for (int j = 0; j < 7; ++j) { ew[j] = (const float*)d_in[1 + 2*j]; eb[j] = (const float*)d_in[2 + 2*j]; }
  const float* dw[6]; const float* db[6];
  for (int j = 0; j < 6; ++j) { dw[j] = (const float*)d_in[15 + 2*j]; db[j] = (const float*)d_in[16 + 2*j]; }

  float* ws   = (float*)d_ws;
  float* bufA = ws;                       // 32*32*128*128 = 16,777,216 floats
  float* bufB = bufA + 16777216;
  float* R    = bufB + 16777216;          // 32*128*256 = 1,048,576
  float* maps = R + 1048576;
  float* S    = maps + 1048576;           // 4096
  float* Sh   = S + 4096;
  float* Sw   = Sh + 4096;
  float* outp = (float*)d_out;            // 32*16*128*128

  dim3 blk(256);

  // ---- encoder ---- all heavy layers at 2048 blocks (8 blk/CU, 32 waves/CU)
  conv_s1r2<ACT_ID,    4,4,3>  <<<dim3(B*8,   8), blk, 0, stream>>>(x,    ew[0], eb[0], bufA, 32,  128, 128); // 2048
  conv_s1r2<ACT_ID,    4,4,32> <<<dim3(B*8,   8), blk, 0, stream>>>(bufA, ew[1], eb[1], bufB, 32,  128, 128); // 2048
  conv_s2<ACT_LRELU,   4,4,32> <<<dim3(B*16,  4), blk, 0, stream>>>(bufB, ew[2], eb[2], bufA, 64,  128, 128); // 2048
  conv_s1r2<ACT_LRELU, 2,4,64> <<<dim3(B*32,  2), blk, 0, stream>>>(bufA, ew[3], eb[3], bufB, 64,  64,  64);  // 2048
  conv_s2<ACT_LRELU,   2,4,64> <<<dim3(B*64,  1), blk, 0, stream>>>(bufB, ew[4], eb[4], bufA, 128, 64,  64);  // 2048
  conv_s1r2<ACT_LRELU, 2,2,128><<<dim3(B*64,  1), blk, 0, stream>>>(bufA, ew[5], eb[5], bufB, 128, 32,  32);  // 2048
  conv_s2<ACT_SOFTPLUS,4,1,128><<<dim3(B*32,  1), blk, 0, stream>>>(bufB, ew[6], eb[6], R,    128, 32,  32);  // 1024

  // ---- keypoint bottleneck ----
  kp_reduce<<<dim3(B*128), dim3(64), 0, stream>>>(R, S, Sh, Sw);
  kp_maps  <<<dim3(B*128), blk, 0, stream>>>(S, Sh, Sw, maps, 128);

  // ---- decoder ----
  tconv<ACT_RELU,   2,128>  <<<dim3(B*32,  1), blk, 0, stream>>>(maps, dw[0], db[0], bufA, 64, 16);           // 1024
  conv_s1r2<ACT_RELU,2,2,64><<<dim3(B*32,  1), blk, 0, stream>>>(bufA, dw[1], db[1], bufB, 64, 32, 32);       // 1024
  tconv<ACT_RELU,   4,64>   <<<dim3(B*8,   4), blk, 0, stream>>>(bufB, dw[2], db[2], bufA, 32, 32);           // 1024
  conv_s1r2<ACT_RELU,1,4,32><<<dim3(B*32,  2), blk, 0, stream>>>(bufA, dw[3], db[3], bufB, 32, 64, 64);       // 2048
  tconv<ACT_RELU,   8,32>   <<<dim3(B*2,  16), blk, 0, stream>>>(bufB, dw[4], db[4], bufA, 16, 64);           // 1024
  conv_s1r2<ACT_RELU,2,4,16><<<dim3(B*8,   8), blk, 0, stream>>>(bufA, dw[5], db[5], outp, 16, 128, 128);     // 2048
}

// Round 8
// 1275.324 us; speedup vs baseline: 1.5033x; 1.5033x over previous
//
#include <hip/hip_runtime.h>
#include <math.h>

// ULOSD keypoint autoencoder, fp32 direct convolutions.
// Round 11: round-10 FAILED correctness -- dec5 launched conv_s1r2<...,2,4,16>
// (cogs=8, needs grid B*8) with R7's NC=4 grid (B*4): batches 16..31 never
// written, absmax 0.1. Fixed by restoring R7's exact dec5 config
// conv_s1r2<RELU,4,4,16> @ dim3(B*4,8). All 13 launches re-audited:
// cogs*NC==Cout and grid.y*256>=items everywhere.
// Experiment (unchanged, still unmeasured): ci-loop unroll 2 in conv_s1r2 vs
// R7's unroll 1 (R6 validated on 1-row tile: VALUBusy 43->70%). ~24 loads of
// 2 channels batch ahead of ~2300 FMA-cycles; acc 64 + 2x24 transient + addr
// ~= 145-165 regs < 170 (3-wave boundary). No pins, no persistent arrays.

enum { ACT_ID = 0, ACT_LRELU = 1, ACT_SOFTPLUS = 2, ACT_RELU = 3 };

template<int ACT>
__device__ __forceinline__ float act_fn(float x) {
  if (ACT == ACT_LRELU)    return x >= 0.f ? x : 0.2f * x;
  if (ACT == ACT_SOFTPLUS) return fmaxf(x, 0.f) + log1pf(expf(-fabsf(x)));
  if (ACT == ACT_RELU)     return fmaxf(x, 0.f);
  return x;
}

// ---------------- stride-1 3x3 SAME conv, 2 output rows x CPT cols, NC couts ---
template<int ACT, int NC, int CPT, int CIN>
__global__ __launch_bounds__(256)
void conv_s1r2(const float* __restrict__ in, const float* __restrict__ w,
               const float* __restrict__ bias, float* __restrict__ out,
               int Cout, int H, int W) {
  const int cogs = Cout / NC;
  const int gx  = blockIdx.x;           // b*cogs + cog
  const int cog = gx % cogs;
  const int b   = gx / cogs;
  const int co0 = cog * NC;
  const int Wq  = W / CPT;
  const int Hp  = H >> 1;               // row pairs
  const int items = Hp * Wq;
  const int item  = blockIdx.y * 256 + threadIdx.x;
  if (item >= items) return;
  const int yp = item / Wq;
  const int x0 = (item - yp * Wq) * CPT;
  const int y0 = 2 * yp;                // output rows y0, y0+1; input y0-1..y0+2

  const int HW = H * W;
  const float* ib = in + (size_t)b * CIN * HW;

  const bool okT = (y0 > 0), okB = (y0 + 2 < H);
  const bool okL = (x0 > 0), okR = (x0 + CPT < W);
  const int xl = okL ? (x0 - 1) : 0;
  const int xr = okR ? (x0 + CPT) : 0;

  float acc[NC][2][CPT];
  #pragma unroll
  for (int u = 0; u < NC; ++u)
    #pragma unroll
    for (int o = 0; o < 2; ++o)
      #pragma unroll
      for (int q = 0; q < CPT; ++q) acc[u][o][q] = 0.f;

  #pragma unroll 2
  for (int ci = 0; ci < CIN; ++ci) {
    const float* p = ib + ci * HW;
    const float* wci = w + ((size_t)co0 * CIN + ci) * 9;
    #pragma unroll
    for (int r = 0; r < 4; ++r) {            // input rows y0-1+r
      const bool ok = (r == 0) ? okT : ((r == 3) ? okB : true);
      const int iy = ok ? (y0 - 1 + r) : 0;
      const float* row = p + iy * W;
      float v[CPT + 2];
      if (CPT == 4) {
        float  lf = row[xl];
        float4 m  = *(const float4*)(row + x0);
        float  rf = row[xr];
        v[0] = (ok && okL) ? lf : 0.f;
        v[1] = ok ? m.x : 0.f;
        v[2] = ok ? m.y : 0.f;
        v[3] = ok ? m.z : 0.f;
        v[4] = ok ? m.w : 0.f;
        v[5] = (ok && okR) ? rf : 0.f;
      } else if (CPT == 2) {
        float  lf = row[xl];
        float2 m  = *(const float2*)(row + x0);   // x0 even -> aligned
        float  rf = row[xr];
        v[0] = (ok && okL) ? lf : 0.f;
        v[1] = ok ? m.x : 0.f;
        v[2] = ok ? m.y : 0.f;
        v[3] = (ok && okR) ? rf : 0.f;
      } else {
        v[0] = (ok && okL) ? row[xl] : 0.f;
        #pragma unroll
        for (int q = 0; q < CPT; ++q) v[1 + q] = ok ? row[x0 + q] : 0.f;
        v[CPT + 1] = (ok && okR) ? row[xr] : 0.f;
      }
      // input row r -> out-row0 with wrow r (r<=2), out-row1 with wrow r-1 (r>=1)
      #pragma unroll
      for (int u = 0; u < NC; ++u) {
        const float* wp = wci + (size_t)u * CIN * 9;   // wave-uniform s_loads
        if (r <= 2) {
          const float w0 = wp[r * 3], w1 = wp[r * 3 + 1], w2 = wp[r * 3 + 2];
          #pragma unroll
          for (int q = 0; q < CPT; ++q)
            acc[u][0][q] += v[q] * w0 + v[q + 1] * w1 + v[q + 2] * w2;
        }
        if (r >= 1) {
          const float w0 = wp[(r-1) * 3], w1 = wp[(r-1) * 3 + 1], w2 = wp[(r-1) * 3 + 2];
          #pragma unroll
          for (int q = 0; q < CPT; ++q)
            acc[u][1][q] += v[q] * w0 + v[q + 1] * w1 + v[q + 2] * w2;
        }
      }
    }
  }

  #pragma unroll
  for (int u = 0; u < NC; ++u) {
    const float bv = bias[co0 + u];
    float* op = out + ((size_t)(b * Cout + co0 + u) * H + y0) * W + x0;
    #pragma unroll
    for (int o = 0; o < 2; ++o) {
      float* opo = op + o * W;
      if (CPT == 4) {
        float4 r4;
        r4.x = act_fn<ACT>(acc[u][o][0] + bv);
        r4.y = act_fn<ACT>(acc[u][o][1] + bv);
        r4.z = act_fn<ACT>(acc[u][o][2] + bv);
        r4.w = act_fn<ACT>(acc[u][o][3] + bv);
        *(float4*)opo = r4;
      } else if (CPT == 2) {
        float2 r2;
        r2.x = act_fn<ACT>(acc[u][o][0] + bv);
        r2.y = act_fn<ACT>(acc[u][o][1] + bv);
        *(float2*)opo = r2;
      } else {
        #pragma unroll
        for (int q = 0; q < CPT; ++q) opo[q] = act_fn<ACT>(acc[u][o][q] + bv);
      }
    }
  }
}

// ---------------- stride-1 3x3 SAME conv, 1 row (dec1 only) --------------------
template<int ACT, int NC, int CPT, int CIN>
__global__ __launch_bounds__(256)
void conv_s1(const float* __restrict__ in, const float* __restrict__ w,
             const float* __restrict__ bias, float* __restrict__ out,
             int Cout, int H, int W) {
  const int cogs = Cout / NC;
  const int gx  = blockIdx.x;
  const int cog = gx % cogs;
  const int b   = gx / cogs;
  const int co0 = cog * NC;
  const int Wq  = W / CPT;
  const int items = H * Wq;
  const int item  = blockIdx.y * 256 + threadIdx.x;
  if (item >= items) return;
  const int y  = item / Wq;
  const int x0 = (item - y * Wq) * CPT;

  const int HW = H * W;
  const float* ib = in + (size_t)b * CIN * HW;

  const bool okT = (y > 0), okB = (y < H - 1);
  const bool okL = (x0 > 0), okR = (x0 + CPT < W);
  const int ym = okT ? (y - 1) : 0;
  const int yp = okB ? (y + 1) : 0;
  const int xl = okL ? (x0 - 1) : 0;
  const int xr = okR ? (x0 + CPT) : 0;

  float acc[NC][CPT];
  #pragma unroll
  for (int u = 0; u < NC; ++u)
    #pragma unroll
    for (int q = 0; q < CPT; ++q) acc[u][q] = 0.f;

  #pragma unroll 2
  for (int ci = 0; ci < CIN; ++ci) {
    const float* p = ib + ci * HW;
    const float* wci = w + ((size_t)co0 * CIN + ci) * 9;
    #pragma unroll
    for (int dy = 0; dy < 3; ++dy) {
      const int  ry    = (dy == 0) ? ym : ((dy == 1) ? y : yp);
      const bool okRow = (dy == 0) ? okT : ((dy == 1) ? true : okB);
      const float* r = p + ry * W;
      float v[CPT + 2];
      if (CPT == 2) {
        float  lf = r[xl];
        float2 m  = *(const float2*)(r + x0);
        float  rf = r[xr];
        v[0] = (okRow && okL) ? lf : 0.f;
        v[1] = okRow ? m.x : 0.f;
        v[2] = okRow ? m.y : 0.f;
        v[3] = (okRow && okR) ? rf : 0.f;
      } else {
        v[0] = (okRow && okL) ? r[xl] : 0.f;
        #pragma unroll
        for (int q = 0; q < CPT; ++q) v[1 + q] = okRow ? r[x0 + q] : 0.f;
        v[CPT + 1] = (okRow && okR) ? r[xr] : 0.f;
      }
      #pragma unroll
      for (int u = 0; u < NC; ++u) {
        const float* wp = wci + u * CIN * 9 + dy * 3;
        const float w0 = wp[0], w1 = wp[1], w2 = wp[2];
        #pragma unroll
        for (int q = 0; q < CPT; ++q)
          acc[u][q] += v[q] * w0 + v[q + 1] * w1 + v[q + 2] * w2;
      }
    }
  }

  #pragma unroll
  for (int u = 0; u < NC; ++u) {
    const float bv = bias[co0 + u];
    float* op = out + ((size_t)(b * Cout + co0 + u) * H + y) * W + x0;
    if (CPT == 2) {
      float2 r2;
      r2.x = act_fn<ACT>(acc[u][0] + bv);
      r2.y = act_fn<ACT>(acc[u][1] + bv);
      *(float2*)op = r2;
    } else {
      #pragma unroll
      for (int q = 0; q < CPT; ++q) op[q] = act_fn<ACT>(acc[u][q] + bv);
    }
  }
}

// ---------------- stride-2 3x3 SAME conv (pad_before=0, pad_after=1) -----------
template<int ACT, int NC, int CPT, int CIN>
__global__ __launch_bounds__(256)
void conv_s2(const float* __restrict__ in, const float* __restrict__ w,
             const float* __restrict__ bias, float* __restrict__ out,
             int Cout, int H, int W) {
  const int Ho = H >> 1, Wo = W >> 1;
  const int cogs = Cout / NC;
  const int gx  = blockIdx.x;
  const int cog = gx % cogs;
  const int b   = gx / cogs;
  const int co0 = cog * NC;
  const int Wq  = Wo / CPT;
  const int items = Ho * Wq;
  const int item  = blockIdx.y * 256 + threadIdx.x;
  if (item >= items) return;
  const int y  = item / Wq;
  const int x0 = (item - y * Wq) * CPT;
  const int ix = 2 * x0;

  const int HW = H * W;
  const float* ib = in + (size_t)b * CIN * HW;

  const int iy0 = 2 * y, iy1 = 2 * y + 1, iy2 = 2 * y + 2;
  const bool okB = (iy2 < H);
  const int iy2c = okB ? iy2 : 0;
  const bool okR = (ix + 2 * CPT < W);
  const int ixr  = okR ? (ix + 2 * CPT) : 0;

  float acc[NC][CPT];
  #pragma unroll
  for (int u = 0; u < NC; ++u)
    #pragma unroll
    for (int q = 0; q < CPT; ++q) acc[u][q] = 0.f;

  #pragma unroll 2
  for (int ci = 0; ci < CIN; ++ci) {
    const float* p = ib + ci * HW;
    const float* wci = w + ((size_t)co0 * CIN + ci) * 9;
    #pragma unroll
    for (int dy = 0; dy < 3; ++dy) {
      const int  ry    = (dy == 0) ? iy0 : ((dy == 1) ? iy1 : iy2c);
      const bool okRow = (dy < 2) || okB;
      const float* r = p + ry * W;
      float v[2 * CPT + 1];
      if (CPT == 4) {
        float4 m0 = *(const float4*)(r + ix);
        float4 m1 = *(const float4*)(r + ix + 4);
        float  rf = r[ixr];
        v[0] = okRow ? m0.x : 0.f; v[1] = okRow ? m0.y : 0.f;
        v[2] = okRow ? m0.z : 0.f; v[3] = okRow ? m0.w : 0.f;
        v[4] = okRow ? m1.x : 0.f; v[5] = okRow ? m1.y : 0.f;
        v[6] = okRow ? m1.z : 0.f; v[7] = okRow ? m1.w : 0.f;
        v[8] = (okRow && okR) ? rf : 0.f;
      } else if (CPT == 2) {
        float4 m0 = *(const float4*)(r + ix);
        float  rf = r[ixr];
        v[0] = okRow ? m0.x : 0.f; v[1] = okRow ? m0.y : 0.f;
        v[2] = okRow ? m0.z : 0.f; v[3] = okRow ? m0.w : 0.f;
        v[4] = (okRow && okR) ? rf : 0.f;
      } else {
        float2 m0 = *(const float2*)(r + ix);
        float  rf = r[ixr];
        v[0] = okRow ? m0.x : 0.f; v[1] = okRow ? m0.y : 0.f;
        v[2] = (okRow && okR) ? rf : 0.f;
      }
      #pragma unroll
      for (int u = 0; u < NC; ++u) {
        const float* wp = wci + u * CIN * 9 + dy * 3;
        const float w0 = wp[0], w1 = wp[1], w2 = wp[2];
        #pragma unroll
        for (int q = 0; q < CPT; ++q)
          acc[u][q] += v[2*q] * w0 + v[2*q + 1] * w1 + v[2*q + 2] * w2;
      }
    }
  }

  #pragma unroll
  for (int u = 0; u < NC; ++u) {
    const float bv = bias[co0 + u];
    float* op = out + ((size_t)(b * Cout + co0 + u) * Ho + y) * Wo + x0;
    if (CPT == 4) {
      float4 r4;
      r4.x = act_fn<ACT>(acc[u][0] + bv);
      r4.y = act_fn<ACT>(acc[u][1] + bv);
      r4.z = act_fn<ACT>(acc[u][2] + bv);
      r4.w = act_fn<ACT>(acc[u][3] + bv);
      *(float4*)op = r4;
    } else if (CPT == 2) {
      float2 r2;
      r2.x = act_fn<ACT>(acc[u][0] + bv);
      r2.y = act_fn<ACT>(acc[u][1] + bv);
      *(float2*)op = r2;
    } else {
      #pragma unroll
      for (int q = 0; q < CPT; ++q) op[q] = act_fn<ACT>(acc[u][q] + bv);
    }
  }
}

// ---------------- stride-2 3x3 SAME transposed conv ----------------------------
// out[2i,2j]=xtl*w00+xtr*w02+xbl*w20+xbr*w22; out[2i,2j+1]=xtr*w01+xbr*w21
// out[2i+1,2j]=xbl*w10+xbr*w12;               out[2i+1,2j+1]=xbr*w11
template<int ACT, int NC, int CIN>
__global__ __launch_bounds__(256)
void tconv(const float* __restrict__ in, const float* __restrict__ w,
           const float* __restrict__ bias, float* __restrict__ out,
           int Cout, int Hin) {
  const int cogs = Cout / NC;
  const int gx  = blockIdx.x;
  const int cog = gx % cogs;
  const int b   = gx / cogs;
  const int co0 = cog * NC;
  const int items = Hin * Hin;
  const int item  = blockIdx.y * 256 + threadIdx.x;
  if (item >= items) return;
  const int i = item / Hin;
  const int j = item - i * Hin;

  const float* ib = in + (size_t)b * CIN * items;
  const bool okT = (i > 0), okL = (j > 0);
  const int im = okT ? i - 1 : 0;
  const int jm = okL ? j - 1 : 0;

  float a00[NC], a01[NC], a10[NC], a11[NC];
  #pragma unroll
  for (int u = 0; u < NC; ++u) { a00[u]=0.f; a01[u]=0.f; a10[u]=0.f; a11[u]=0.f; }

  #pragma unroll 2
  for (int ci = 0; ci < CIN; ++ci) {
    const float* p = ib + ci * items;
    float xtl = p[im*Hin + jm]; xtl = (okT && okL) ? xtl : 0.f;
    float xtr = p[im*Hin + j];  xtr = okT ? xtr : 0.f;
    float xbl = p[i*Hin + jm];  xbl = okL ? xbl : 0.f;
    float xbr = p[i*Hin + j];
    const float* wci = w + ((size_t)co0 * CIN + ci) * 9;
    #pragma unroll
    for (int u = 0; u < NC; ++u) {
      const float* wp = wci + u * CIN * 9;
      const float w00 = wp[0], w01 = wp[1], w02 = wp[2];
      const float w10 = wp[3], w11 = wp[4], w12 = wp[5];
      const float w20 = wp[6], w21 = wp[7], w22 = wp[8];
      a00[u] += xtl*w00 + xtr*w02 + xbl*w20 + xbr*w22;
      a01[u] += xtr*w01 + xbr*w21;
      a10[u] += xbl*w10 + xbr*w12;
      a11[u] += xbr*w11;
    }
  }

  const int Ho = Hin * 2;
  #pragma unroll
  for (int u = 0; u < NC; ++u) {
    const float bv = bias[co0 + u];
    float* op = out + (size_t)(b * Cout + co0 + u) * Ho * Ho + (2*i) * Ho + 2*j;
    float2 t0, t1;
    t0.x = act_fn<ACT>(a00[u] + bv); t0.y = act_fn<ACT>(a01[u] + bv);
    t1.x = act_fn<ACT>(a10[u] + bv); t1.y = act_fn<ACT>(a11[u] + bv);
    *(float2*)op = t0;
    *(float2*)(op + Ho) = t1;
  }
}

// ---------------- keypoint reductions: S = sum R, Sh = sum R*h, Sw = sum R*w ----
__global__ __launch_bounds__(64)
void kp_reduce(const float* __restrict__ R, float* __restrict__ S,
               float* __restrict__ Sh, float* __restrict__ Sw) {
  const int bk = blockIdx.x;       // b*K + k, 16x16 maps
  const int t = threadIdx.x;       // 64
  const float* p = R + (size_t)bk * 256;
  float s = 0.f, sh = 0.f, sw = 0.f;
  #pragma unroll
  for (int q = 0; q < 4; ++q) {
    int idx = t + q * 64;
    float v = p[idx];
    s  += v;
    sh += v * (float)(idx >> 4);
    sw += v * (float)(idx & 15);
  }
  #pragma unroll
  for (int off = 32; off > 0; off >>= 1) {
    s  += __shfl_down(s, off);
    sh += __shfl_down(sh, off);
    sw += __shfl_down(sw, off);
  }
  if (t == 0) { S[bk] = s; Sh[bk] = sh; Sw[bk] = sw; }
}

// ---------------- gaussian blob maps -------------------------------------------
__global__ __launch_bounds__(256)
void kp_maps(const float* __restrict__ S, const float* __restrict__ Sh,
             const float* __restrict__ Sw, float* __restrict__ maps, int K) {
  const int bk = blockIdx.x;
  const int b = bk / K;
  const int t = threadIdx.x;       // 256 = 16x16
  const float s   = S[bk];
  const float den = S[b * K + (K - 1)];
  const float mu  = s * (1.0f / 256.0f);
  const float c0  = Sh[bk] / den;
  const float c1  = Sw[bk] / den;
  const float u = (float)(t >> 4);
  const float v = (float)(t & 15);
  const float d2 = (u - c0) * (u - c0) + (v - c1) * (v - c1);
  maps[(size_t)bk * 256 + t] = mu * expf(-0.5f * d2);
}

extern "C" void kernel_launch(void* const* d_in, const int* in_sizes, int n_in,
                              void* d_out, int out_size, void* d_ws, size_t ws_size,
                              hipStream_t stream) {
  const int B = 32;  // 4 * 8
  const float* x = (const float*)d_in[0];
  const float* ew[7]; const float* eb[7];
  for (int j = 0; j < 7; ++j) { ew[j] = (const float*)d_in[1 + 2*j]; eb[j] = (const float*)d_in[2 + 2*j]; }
  const float* dw[6]; const float* db[6];
  for (int j = 0; j < 6; ++j) { dw[j] = (const float*)d_in[15 + 2*j]; db[j] = (const float*)d_in[16 + 2*j]; }

  float* ws   = (float*)d_ws;
  float* bufA = ws;                       // 32*32*128*128 = 16,777,216 floats
  float* bufB = bufA + 16777216;
  float* R    = bufB + 16777216;          // 32*128*256 = 1,048,576
  float* maps = R + 1048576;
  float* S    = maps + 1048576;           // 4096
  float* Sh   = S + 4096;
  float* Sw   = Sh + 4096;
  float* outp = (float*)d_out;            // 32*16*128*128

  dim3 blk(256);

  // ---- encoder ---- (round-7 grids/tiles exactly; only the unroll changed)
  conv_s1r2<ACT_ID,    8,4,3>  <<<dim3(B*4,   8), blk, 0, stream>>>(x,    ew[0], eb[0], bufA, 32,  128, 128); // 1024 blk
  conv_s1r2<ACT_ID,    8,4,32> <<<dim3(B*4,   8), blk, 0, stream>>>(bufA, ew[1], eb[1], bufB, 32,  128, 128); // 1024 blk
  conv_s2<ACT_LRELU,   8,4,32> <<<dim3(B*8,   4), blk, 0, stream>>>(bufB, ew[2], eb[2], bufA, 64,  128, 128); // 1024 blk
  conv_s1r2<ACT_LRELU, 4,4,64> <<<dim3(B*16,  2), blk, 0, stream>>>(bufA, ew[3], eb[3], bufB, 64,  64,  64);  // 1024 blk
  conv_s2<ACT_LRELU,   8,2,64> <<<dim3(B*16,  2), blk, 0, stream>>>(bufB, ew[4], eb[4], bufA, 128, 64,  64);  // 1024 blk
  conv_s1r2<ACT_LRELU, 4,2,128><<<dim3(B*32,  1), blk, 0, stream>>>(bufA, ew[5], eb[5], bufB, 128, 32,  32);  // 1024 blk
  conv_s2<ACT_SOFTPLUS,4,1,128><<<dim3(B*32,  1), blk, 0, stream>>>(bufB, ew[6], eb[6], R,    128, 32,  32);  // 1024 blk

  // ---- keypoint bottleneck ----
  kp_reduce<<<dim3(B*128), dim3(64), 0, stream>>>(R, S, Sh, Sw);
  kp_maps  <<<dim3(B*128), blk, 0, stream>>>(S, Sh, Sw, maps, 128);

  // ---- decoder ----
  tconv<ACT_RELU,   2,128> <<<dim3(B*32,  1), blk, 0, stream>>>(maps, dw[0], db[0], bufA, 64, 16);            // 1024 blk
  conv_s1<ACT_RELU, 4,2,64><<<dim3(B*16,  2), blk, 0, stream>>>(bufA, dw[1], db[1], bufB, 64, 32, 32);        // 1024 blk
  tconv<ACT_RELU,   4,64>  <<<dim3(B*8,   4), blk, 0, stream>>>(bufB, dw[2], db[2], bufA, 32, 32);            // 1024 blk
  conv_s1r2<ACT_RELU,4,2,32><<<dim3(B*8,   4), blk, 0, stream>>>(bufA, dw[3], db[3], bufB, 32, 64, 64);       // 1024 blk
  tconv<ACT_RELU,   8,32>  <<<dim3(B*2,  16), blk, 0, stream>>>(bufB, dw[4], db[4], bufA, 16, 64);            // 1024 blk
  conv_s1r2<ACT_RELU,4,4,16><<<dim3(B*4,   8), blk, 0, stream>>>(bufA, dw[5], db[5], outp, 16, 128, 128);     // 1024 blk
}